// Round 4
// baseline (12037.695 us; speedup 1.0000x reference)
//
#include <hip/hip_runtime.h>
#include <stdint.h>

#define Bdim 4
#define Tdim 2048
#define Vdim 32000
#define Hdim 512
#define MROWS (Bdim * Tdim)   // 8192

typedef unsigned short u16;
typedef __bf16 bf16x8 __attribute__((ext_vector_type(8)));
typedef float f32x4 __attribute__((ext_vector_type(4)));
typedef uint32_t u32x4 __attribute__((ext_vector_type(4)));

__device__ __forceinline__ u16 f2bf(float f) {
  union { float f; uint32_t u; } a; a.f = f;
  uint32_t r = a.u + 0x7FFFu + ((a.u >> 16) & 1u);
  return (u16)(r >> 16);
}

// ---------------- embedding gather -> bf16 ----------------
__global__ void k_gather(const int* __restrict__ x, const float* __restrict__ embed,
                         u16* __restrict__ E) {
  int idx = blockIdx.x * 256 + threadIdx.x;   // one float4 per thread
  int row = idx >> 7;                          // 128 float4 per row
  int c4  = (idx & 127) << 2;
  int tok = x[row];
  const float4 v = *(const float4*)(embed + (size_t)tok * Hdim + c4);
  *(ushort4*)(E + (size_t)row * Hdim + c4) =
      make_ushort4(f2bf(v.x), f2bf(v.y), f2bf(v.z), f2bf(v.w));
}

// ---------------- fp32 -> bf16 convert ----------------
__global__ void k_f2b(const float* __restrict__ in, u16* __restrict__ out, int n4) {
  int idx = blockIdx.x * 256 + threadIdx.x;
  if (idx >= n4) return;
  const float4 v = *(const float4*)(in + (size_t)idx * 4);
  *(ushort4*)(out + (size_t)idx * 4) =
      make_ushort4(f2bf(v.x), f2bf(v.y), f2bf(v.z), f2bf(v.w));
}

// ---------------- bf16 MFMA GEMM: C = A @ Bw^T + bias1 (+bias2) ----------------
__device__ __forceinline__ void g2l16(const void* g, void* l) {
  __builtin_amdgcn_global_load_lds(
      (const __attribute__((address_space(1))) uint32_t*)g,
      (__attribute__((address_space(3))) uint32_t*)l, 16, 0, 0);
}

__global__ __launch_bounds__(256, 2) void k_gemm(
    const u16* __restrict__ A, const u16* __restrict__ Bw, float* __restrict__ C,
    const float* __restrict__ bias1, const float* __restrict__ bias2,
    int M, int N, int K, int ntN)
{
  __shared__ u16 Al[128 * 64];
  __shared__ u16 Bl[128 * 64];
  const int bid = blockIdx.x;
  const int mt = bid / ntN, nt = bid % ntN;
  const int m0 = mt << 7, n0 = nt << 7;
  const int tid = threadIdx.x;
  const int l = tid & 63, w = tid >> 6;
  const int wy = w >> 1, wx = w & 1;
  const int frow = l & 15, fk = (l >> 4) << 3;

  f32x4 acc[4][4];
  #pragma unroll
  for (int a = 0; a < 4; ++a)
    #pragma unroll
    for (int b = 0; b < 4; ++b) acc[a][b] = f32x4{0.f, 0.f, 0.f, 0.f};

  for (int kb = 0; kb < K; kb += 64) {
    __syncthreads();
    #pragma unroll
    for (int is = 0; is < 4; ++is) {
      const int off = tid * 16 + is * 4096;      // byte offset inside 16KB tile
      const int lrow = off >> 7, lcolB = off & 127;
      g2l16(A  + (size_t)(m0 + lrow) * K + kb + (lcolB >> 1), (char*)Al + off);
      g2l16(Bw + (size_t)(n0 + lrow) * K + kb + (lcolB >> 1), (char*)Bl + off);
    }
    __syncthreads();
    #pragma unroll
    for (int ks = 0; ks < 2; ++ks) {
      bf16x8 af[4], bfr[4];
      #pragma unroll
      for (int mi = 0; mi < 4; ++mi)
        af[mi] = *(const bf16x8*)&Al[((wy * 64 + mi * 16 + frow) << 6) + ks * 32 + fk];
      #pragma unroll
      for (int ni = 0; ni < 4; ++ni)
        bfr[ni] = *(const bf16x8*)&Bl[((wx * 64 + ni * 16 + frow) << 6) + ks * 32 + fk];
      #pragma unroll
      for (int mi = 0; mi < 4; ++mi)
        #pragma unroll
        for (int ni = 0; ni < 4; ++ni)
          acc[mi][ni] = __builtin_amdgcn_mfma_f32_16x16x32_bf16(af[mi], bfr[ni], acc[mi][ni], 0, 0, 0);
    }
  }
  #pragma unroll
  for (int ni = 0; ni < 4; ++ni) {
    const int col = n0 + wx * 64 + ni * 16 + (l & 15);
    float bv = bias1[col];
    if (bias2) bv += bias2[col];
    #pragma unroll
    for (int mi = 0; mi < 4; ++mi) {
      const int row = m0 + wy * 64 + mi * 16 + ((l >> 4) << 2);
      #pragma unroll
      for (int r = 0; r < 4; ++r)
        C[(size_t)(row + r) * N + col] = acc[mi][ni][r] + bv;
    }
  }
}

// ---------------- persistent RNN scan ----------------
// grid=128, survivors blockIdx%8==0 (XCD-0 heuristic; correctness placement-
// independent). 16 real WGs x 256 threads. WGs 0..7: layer0 (64 neurons);
// 8..15: layer1. Each WAVE polls+stages the full h [4B x 512] itself:
// no __syncthreads in the loop. Polls: inline-asm sc0 loads (same-XCD L2
// fast path), escalating to proven agent-scope atomics after 2 tries.
#define SENT 0xFFFFFFFFu

__device__ __forceinline__ void astore(uint32_t* p, uint32_t v) {
  __hip_atomic_store(p, v, __ATOMIC_RELAXED, __HIP_MEMORY_SCOPE_AGENT);
}
__device__ __forceinline__ uint32_t aload(const uint32_t* p) {
  return __hip_atomic_load(p, __ATOMIC_RELAXED, __HIP_MEMORY_SCOPE_AGENT);
}

// fused issue+wait, L2-scope (sc0: bypass L1, hit XCD L2)
__device__ __forceinline__ void pollload(const uint32_t* p, u32x4& a, u32x4& b,
                                         u32x4& c, u32x4& d) {
  asm volatile(
      "global_load_dwordx4 %0, %4, off sc0\n\t"
      "global_load_dwordx4 %1, %4, off offset:16 sc0\n\t"
      "global_load_dwordx4 %2, %4, off offset:32 sc0\n\t"
      "global_load_dwordx4 %3, %4, off offset:48 sc0\n\t"
      "s_waitcnt vmcnt(0)"
      : "=&v"(a), "=&v"(b), "=&v"(c), "=&v"(d)
      : "v"(p) : "memory");
  __builtin_amdgcn_sched_barrier(0);
}
// split issue (no wait) for latency overlap
__device__ __forceinline__ void pissue(const uint32_t* p, u32x4& a, u32x4& b,
                                       u32x4& c, u32x4& d) {
  asm volatile(
      "global_load_dwordx4 %0, %4, off sc0\n\t"
      "global_load_dwordx4 %1, %4, off offset:16 sc0\n\t"
      "global_load_dwordx4 %2, %4, off offset:32 sc0\n\t"
      "global_load_dwordx4 %3, %4, off offset:48 sc0"
      : "=&v"(a), "=&v"(b), "=&v"(c), "=&v"(d)
      : "v"(p) : "memory");
}
__device__ __forceinline__ void pwait(u32x4& a, u32x4& b, u32x4& c, u32x4& d) {
  asm volatile("s_waitcnt vmcnt(0)"
               : "+v"(a), "+v"(b), "+v"(c), "+v"(d) :: "memory");
  __builtin_amdgcn_sched_barrier(0);
}
__device__ __forceinline__ bool any_sent(const u32x4& a, const u32x4& b,
                                         const u32x4& c, const u32x4& d) {
  bool bad = false;
  #pragma unroll
  for (int j = 0; j < 4; ++j)
    bad |= (a[j] == SENT) | (b[j] == SENT) | (c[j] == SENT) | (d[j] == SENT);
  return bad;
}
__device__ __forceinline__ void respin(const uint32_t* p, u32x4& a, u32x4& b,
                                       u32x4& c, u32x4& d) {
  int tr = 0;
  while (any_sent(a, b, c, d)) {
    if (tr < 2) {
      pollload(p, a, b, c, d);
    } else {   // escalation: proven agent-scope path (placement-independent)
      #pragma unroll
      for (int j = 0; j < 4; ++j) {
        if (a[j] == SENT) a[j] = aload(p + j);
        if (b[j] == SENT) b[j] = aload(p + 4 + j);
        if (c[j] == SENT) c[j] = aload(p + 8 + j);
        if (d[j] == SENT) d[j] = aload(p + 12 + j);
      }
    }
    ++tr;
  }
}
__device__ __forceinline__ void spin16(const uint32_t* p, u32x4& a, u32x4& b,
                                       u32x4& c, u32x4& d) {
  pollload(p, a, b, c, d);
  respin(p, a, b, c, d);
}
__device__ __forceinline__ void spin_word(const uint32_t* p) {
  uint32_t v;
  asm volatile("global_load_dword %0, %1, off sc0\n\ts_waitcnt vmcnt(0)"
               : "=&v"(v) : "v"(p) : "memory");
  __builtin_amdgcn_sched_barrier(0);
  int tr = 0;
  while (v == SENT) {
    if (tr < 2)
      asm volatile("global_load_dword %0, %1, off sc0\n\ts_waitcnt vmcnt(0)"
                   : "=&v"(v) : "v"(p) : "memory");
    else
      v = aload(p);
    ++tr;
  }
  __builtin_amdgcn_sched_barrier(0);
}
__device__ __forceinline__ void lds_guard() {   // WAR guard, replaces dbuf
  asm volatile("s_waitcnt lgkmcnt(0)" ::: "memory");
  __builtin_amdgcn_sched_barrier(0);
}

#define STAGE(base, A, B, C, D) do {                      \
    uint32_t* _d = (base) + sb * 264 + sq * 16;           \
    *(u32x4*)(_d)      = (A); *(u32x4*)(_d + 4)  = (B);   \
    *(u32x4*)(_d + 8)  = (C); *(u32x4*)(_d + 12) = (D); } while (0)

template <bool IS_L1>
__device__ __forceinline__ void scan_wg(
    const float* __restrict__ X0,
    const float* __restrict__ W1,   // L0: Whh0 ; L1: Wih1
    const float* __restrict__ W2,   // L1: Whh1
    const float* __restrict__ bi1, const float* __restrict__ bi2,
    uint32_t* __restrict__ H0b, uint32_t* __restrict__ H1b,
    float* __restrict__ hfin, int wgs, uint32_t* hs)
{
  constexpr int NB = IS_L1 ? 32 : 16;
  const int tid = threadIdx.x;
  const int wv  = tid >> 6;
  const int l   = tid & 63;
  const int n   = l & 15;            // neuron-within-wave / D col
  const int cq  = l >> 4;            // k-quarter
  const int ng  = wgs * 64 + wv * 16 + n;
  const int fb  = n & 3;             // A-frag batch row (rows 4-15 dup)
  const int sb  = l >> 4;            // staging batch (lane owns one 64B line)
  const int sq  = l & 15;            // staging 16-dword segment

  uint32_t* hsA = hs + wv * 1056;           // per-wave state A (1056 dw, 528 u16/row)
  uint32_t* hsB = hs + 4224 + wv * 1056;    // state B (L1 only)
  const u16* sA16 = (const u16*)hsA;
  const u16* sB16 = (const u16*)hsB;

  // B-fragments in registers: lane (n,cq) block j holds W[ng][j*32+cq*8+e]
  bf16x8 bw[NB];
  #pragma unroll
  for (int j = 0; j < NB; ++j) {
    const float* wrow;
    int koff;
    if constexpr (IS_L1) {
      if (j < 16) { wrow = W1 + (size_t)ng * Hdim; koff = j * 32; }
      else        { wrow = W2 + (size_t)ng * Hdim; koff = (j - 16) * 32; }
    } else        { wrow = W1 + (size_t)ng * Hdim; koff = j * 32; }
    const float4 a = *(const float4*)(wrow + koff + cq * 8);
    const float4 b = *(const float4*)(wrow + koff + cq * 8 + 4);
    bw[j][0] = (__bf16)a.x; bw[j][1] = (__bf16)a.y;
    bw[j][2] = (__bf16)a.z; bw[j][3] = (__bf16)a.w;
    bw[j][4] = (__bf16)b.x; bw[j][5] = (__bf16)b.y;
    bw[j][6] = (__bf16)b.z; bw[j][7] = (__bf16)b.w;
  }
  float bias = 0.f;
  if constexpr (IS_L1) bias = bi1[ng] + bi2[ng];

  uint32_t* const Hout = IS_L1 ? H1b : H0b;

  #pragma unroll 1
  for (int t = 0; t < Tdim; ++t) {
    f32x4 ac[4];
    #pragma unroll
    for (int q = 0; q < 4; ++q) ac[q] = f32x4{0.f, 0.f, 0.f, 0.f};
    float hv[4], hp[4];

    if constexpr (!IS_L1) {
      // ---------------- layer 0 ----------------
      u32x4 a, b, c, d;
      if (t > 0)
        spin16(H0b + ((size_t)sb * Tdim + (t - 1)) * 256 + sq * 16, a, b, c, d);
      float x0v[4];
      #pragma unroll
      for (int r = 0; r < 4; ++r)
        x0v[r] = X0[((size_t)r * Tdim + t) * Hdim + ng];  // in flight over stage+MFMA
      if (t > 0) {
        lds_guard();
        STAGE(hsA, a, b, c, d);
        #pragma unroll
        for (int j = 0; j < 16; ++j) {
          const bf16x8 af = *(const bf16x8*)&sA16[fb * 528 + j * 32 + cq * 8];
          ac[j & 3] = __builtin_amdgcn_mfma_f32_16x16x32_bf16(af, bw[j], ac[j & 3], 0, 0, 0);
        }
      }
      const f32x4 s = (ac[0] + ac[1]) + (ac[2] + ac[3]);
      #pragma unroll
      for (int r = 0; r < 4; ++r) hv[r] = tanhf(s[r] + x0v[r]);
      #pragma unroll
      for (int r = 0; r < 4; ++r) hp[r] = __shfl_xor(hv[r], 1);
      if (cq == 0 && !(n & 1)) {
        #pragma unroll
        for (int r = 0; r < 4; ++r) {
          const uint32_t wd = (uint32_t)f2bf(hv[r]) | ((uint32_t)f2bf(hp[r]) << 16);
          astore(&Hout[((size_t)r * Tdim + t) * 256 + (ng >> 1)], wd);
        }
      }
      if (cq == 0 && t == Tdim - 1) {
        #pragma unroll
        for (int r = 0; r < 4; ++r) hfin[r * Hdim + ng] = hv[r];
      }
      // throttle: stay <=128+16 steps ahead of L1 (keeps H0 polls L2-hot)
      if (t >= 128 && (t & 15) == 0)
        spin_word(H1b + (size_t)(t - 128) * 256);
    } else {
      // ---------------- layer 1 ----------------
      u32x4 a, b, c, d, e, f, g, h2;
      if (t > 0) {
        // self-recurrence first: h1[t-1]
        spin16(H1b + ((size_t)sb * Tdim + (t - 1)) * 256 + sq * 16, e, f, g, h2);
        lds_guard();
        STAGE(hsB, e, f, g, h2);
        // overlap: issue h0[t] poll, hide under the Whh1 MFMA block (T14)
        pissue(H0b + ((size_t)sb * Tdim + t) * 256 + sq * 16, a, b, c, d);
        #pragma unroll
        for (int j = 0; j < 16; ++j) {
          const bf16x8 af = *(const bf16x8*)&sB16[fb * 528 + j * 32 + cq * 8];
          ac[j & 3] = __builtin_amdgcn_mfma_f32_16x16x32_bf16(af, bw[16 + j], ac[j & 3], 0, 0, 0);
        }
        pwait(a, b, c, d);
        respin(H0b + ((size_t)sb * Tdim + t) * 256 + sq * 16, a, b, c, d);
      } else {
        spin16(H0b + ((size_t)sb * Tdim + 0) * 256 + sq * 16, a, b, c, d);
      }
      lds_guard();
      STAGE(hsA, a, b, c, d);
      #pragma unroll
      for (int j = 0; j < 16; ++j) {
        const bf16x8 af = *(const bf16x8*)&sA16[fb * 528 + j * 32 + cq * 8];
        ac[j & 3] = __builtin_amdgcn_mfma_f32_16x16x32_bf16(af, bw[j], ac[j & 3], 0, 0, 0);
      }
      const f32x4 s = (ac[0] + ac[1]) + (ac[2] + ac[3]);
      #pragma unroll
      for (int r = 0; r < 4; ++r) hv[r] = tanhf(s[r] + bias);
      #pragma unroll
      for (int r = 0; r < 4; ++r) hp[r] = __shfl_xor(hv[r], 1);
      if (cq == 0 && !(n & 1)) {
        #pragma unroll
        for (int r = 0; r < 4; ++r) {
          const uint32_t wd = (uint32_t)f2bf(hv[r]) | ((uint32_t)f2bf(hp[r]) << 16);
          astore(&Hout[((size_t)r * Tdim + t) * 256 + (ng >> 1)], wd);
        }
      }
      if (cq == 0 && t == Tdim - 1) {
        #pragma unroll
        for (int r = 0; r < 4; ++r) hfin[Bdim * Hdim + r * Hdim + ng] = hv[r];
      }
    }
  }
}

__global__ __launch_bounds__(256, 1) void k_scan(
    const float* __restrict__ X0, const float* __restrict__ W_ih,
    const float* __restrict__ W_hh, const float* __restrict__ b_ih,
    const float* __restrict__ b_hh, uint32_t* __restrict__ H0b,
    uint32_t* __restrict__ H1b, float* __restrict__ hfin)
{
  __shared__ __align__(16) uint32_t hs[8448];
  if (blockIdx.x & 7) return;            // survivors -> one XCD (heuristic)
  const int wg = blockIdx.x >> 3;        // 0..15
  if (wg < 8)
    scan_wg<false>(X0, W_hh, nullptr, nullptr, nullptr, H0b, H1b, hfin, wg, hs);
  else
    scan_wg<true>(nullptr, W_ih + Hdim * Hdim, W_hh + Hdim * Hdim,
                  b_ih + Hdim, b_hh + Hdim, H0b, H1b, hfin, wg - 8, hs);
}

// ---------------- launch ----------------
extern "C" void kernel_launch(void* const* d_in, const int* in_sizes, int n_in,
                              void* d_out, int out_size, void* d_ws, size_t ws_size,
                              hipStream_t stream)
{
  const int*   x     = (const int*)d_in[0];
  const float* embed = (const float*)d_in[1];
  const float* W_ih  = (const float*)d_in[2];
  const float* b_ih  = (const float*)d_in[3];
  const float* W_hh  = (const float*)d_in[4];
  const float* b_hh  = (const float*)d_in[5];
  const float* W_out = (const float*)d_in[6];
  const float* b_out = (const float*)d_in[7];
  float* out = (float*)d_out;

  // workspace layout (~75.3 MB)
  char* ws = (char*)d_ws;
  u16* E       = (u16*)ws;                                  // 8192*512 bf16
  u16* Wih0b   = E + (size_t)MROWS * Hdim;                  // 512*512
  u16* Woutb   = Wih0b + Hdim * Hdim;                       // 32000*512
  float* X0    = (float*)(Woutb + (size_t)Vdim * Hdim);     // 8192*512 f32
  uint32_t* H0b = (uint32_t*)(X0 + (size_t)MROWS * Hdim);   // 8192*256 words
  uint32_t* H1b = H0b + (size_t)MROWS * (Hdim / 2);

  k_gather<<<MROWS * (Hdim / 4) / 256, 256, 0, stream>>>(x, embed, E);
  k_f2b<<<(Hdim * Hdim / 4) / 256, 256, 0, stream>>>(W_ih, Wih0b, Hdim * Hdim / 4);
  k_f2b<<<(Vdim * Hdim / 4) / 256, 256, 0, stream>>>(W_out, Woutb, Vdim * Hdim / 4);

  // X0 = E @ Wih0^T + b_ih0 + b_hh0
  k_gemm<<<(MROWS / 128) * (Hdim / 128), 256, 0, stream>>>(
      E, Wih0b, X0, b_ih, b_hh, MROWS, Hdim, Hdim, Hdim / 128);

  hipMemsetAsync(H0b, 0xFF, (size_t)MROWS * (Hdim / 2) * 4, stream);
  hipMemsetAsync(H1b, 0xFF, (size_t)MROWS * (Hdim / 2) * 4, stream);

  float* hfin = out + (size_t)MROWS * Vdim;
  k_scan<<<128, 256, 0, stream>>>(X0, W_ih, W_hh, b_ih, b_hh, H0b, H1b, hfin);

  // out = H1 @ W_out^T + b_out
  k_gemm<<<(MROWS / 128) * (Vdim / 128), 256, 0, stream>>>(
      (const u16*)H1b, Woutb, out, b_out, nullptr, MROWS, Vdim, Hdim, Vdim / 128);
}

// Round 5
// 10960.210 us; speedup vs baseline: 1.0983x; 1.0983x over previous
//
#include <hip/hip_runtime.h>
#include <stdint.h>

#define Bdim 4
#define Tdim 2048
#define Vdim 32000
#define Hdim 512
#define MROWS (Bdim * Tdim)   // 8192

typedef unsigned short u16;
typedef __bf16 bf16x8 __attribute__((ext_vector_type(8)));
typedef float f32x4 __attribute__((ext_vector_type(4)));

__device__ __forceinline__ u16 f2bf(float f) {
  union { float f; uint32_t u; } a; a.f = f;
  uint32_t r = a.u + 0x7FFFu + ((a.u >> 16) & 1u);
  return (u16)(r >> 16);
}

// ---------------- embedding gather -> bf16 ----------------
__global__ void k_gather(const int* __restrict__ x, const float* __restrict__ embed,
                         u16* __restrict__ E) {
  int idx = blockIdx.x * 256 + threadIdx.x;   // one float4 per thread
  int row = idx >> 7;                          // 128 float4 per row
  int c4  = (idx & 127) << 2;
  int tok = x[row];
  const float4 v = *(const float4*)(embed + (size_t)tok * Hdim + c4);
  *(ushort4*)(E + (size_t)row * Hdim + c4) =
      make_ushort4(f2bf(v.x), f2bf(v.y), f2bf(v.z), f2bf(v.w));
}

// ---------------- fp32 -> bf16 convert ----------------
__global__ void k_f2b(const float* __restrict__ in, u16* __restrict__ out, int n4) {
  int idx = blockIdx.x * 256 + threadIdx.x;
  if (idx >= n4) return;
  const float4 v = *(const float4*)(in + (size_t)idx * 4);
  *(ushort4*)(out + (size_t)idx * 4) =
      make_ushort4(f2bf(v.x), f2bf(v.y), f2bf(v.z), f2bf(v.w));
}

// ---------------- bf16 MFMA GEMM: C = A @ Bw^T + bias1 (+bias2) ----------------
// aperm=1: A row m lives at u16 offset (m&2047)*2048 + (m>>11)*512 (the scan's
// [t][b][n] layout); aperm=0: standard row-major [m][K].
__device__ __forceinline__ void g2l16(const void* g, void* l) {
  __builtin_amdgcn_global_load_lds(
      (const __attribute__((address_space(1))) uint32_t*)g,
      (__attribute__((address_space(3))) uint32_t*)l, 16, 0, 0);
}

__global__ __launch_bounds__(256, 2) void k_gemm(
    const u16* __restrict__ A, const u16* __restrict__ Bw, float* __restrict__ C,
    const float* __restrict__ bias1, const float* __restrict__ bias2,
    int M, int N, int K, int ntN, int aperm)
{
  __shared__ u16 Al[128 * 64];
  __shared__ u16 Bl[128 * 64];
  const int bid = blockIdx.x;
  const int mt = bid / ntN, nt = bid % ntN;
  const int m0 = mt << 7, n0 = nt << 7;
  const int tid = threadIdx.x;
  const int l = tid & 63, w = tid >> 6;
  const int wy = w >> 1, wx = w & 1;
  const int frow = l & 15, fk = (l >> 4) << 3;

  f32x4 acc[4][4];
  #pragma unroll
  for (int a = 0; a < 4; ++a)
    #pragma unroll
    for (int b = 0; b < 4; ++b) acc[a][b] = f32x4{0.f, 0.f, 0.f, 0.f};

  for (int kb = 0; kb < K; kb += 64) {
    __syncthreads();
    #pragma unroll
    for (int is = 0; is < 4; ++is) {
      const int off = tid * 16 + is * 4096;      // byte offset inside 16KB tile
      const int lrow = off >> 7, lcolB = off & 127;
      const int mrow = m0 + lrow;
      const size_t arow = aperm
          ? (size_t)(mrow & 2047) * 2048 + (size_t)(mrow >> 11) * 512
          : (size_t)mrow * K;
      g2l16(A  + arow + kb + (lcolB >> 1), (char*)Al + off);
      g2l16(Bw + (size_t)(n0 + lrow) * K + kb + (lcolB >> 1), (char*)Bl + off);
    }
    __syncthreads();
    #pragma unroll
    for (int ks = 0; ks < 2; ++ks) {
      bf16x8 af[4], bfr[4];
      #pragma unroll
      for (int mi = 0; mi < 4; ++mi)
        af[mi] = *(const bf16x8*)&Al[((wy * 64 + mi * 16 + frow) << 6) + ks * 32 + fk];
      #pragma unroll
      for (int ni = 0; ni < 4; ++ni)
        bfr[ni] = *(const bf16x8*)&Bl[((wx * 64 + ni * 16 + frow) << 6) + ks * 32 + fk];
      #pragma unroll
      for (int mi = 0; mi < 4; ++mi)
        #pragma unroll
        for (int ni = 0; ni < 4; ++ni)
          acc[mi][ni] = __builtin_amdgcn_mfma_f32_16x16x32_bf16(af[mi], bfr[ni], acc[mi][ni], 0, 0, 0);
    }
  }
  #pragma unroll
  for (int ni = 0; ni < 4; ++ni) {
    const int col = n0 + wx * 64 + ni * 16 + (l & 15);
    float bv = bias1[col];
    if (bias2) bv += bias2[col];
    #pragma unroll
    for (int mi = 0; mi < 4; ++mi) {
      const int row = m0 + wy * 64 + mi * 16 + ((l >> 4) << 2);
      #pragma unroll
      for (int r = 0; r < 4; ++r)
        C[(size_t)(row + r) * N + col] = acc[mi][ni][r] + bv;
    }
  }
}

// ---------------- persistent RNN scan ----------------
// 64 WGs x 64 threads (1 wave each, no LDS, no barriers).
// WGs 0..31: layer0, 16 neurons each. WGs 32..63: layer1.
// h stored as [t][batch][neuron] bf16 (1024 dwords/step); dword = 2 neurons.
// Value-as-flag: sentinel 0xFFFFFFFF (bf16 NaN pair, unreachable for tanh).
// Consumer lane (n,cq) polls exactly its MFMA A-fragments: batch n&3,
// neurons j*32+cq*8..+8 -> one 16B frag (2 x u64 agent-relaxed loads).
#define SENT 0xFFFFFFFFu

__device__ __forceinline__ uint64_t al64(const uint64_t* p) {
  return __hip_atomic_load(p, __ATOMIC_RELAXED, __HIP_MEMORY_SCOPE_AGENT);
}
__device__ __forceinline__ void astore(uint32_t* p, uint32_t v) {
  __hip_atomic_store(p, v, __ATOMIC_RELAXED, __HIP_MEMORY_SCOPE_AGENT);
}
__device__ __forceinline__ bool fbad(uint64_t a, uint64_t b) {
  return ((uint32_t)a == SENT) | ((uint32_t)(a >> 32) == SENT) |
         ((uint32_t)b == SENT) | ((uint32_t)(b >> 32) == SENT);
}
__device__ __forceinline__ bf16x8 fuse2(uint64_t a, uint64_t b) {
  union { uint64_t u[2]; bf16x8 h; } U;
  U.u[0] = a; U.u[1] = b;
  return U.h;
}
__device__ __forceinline__ float fast_tanh(float x) {   // 1 - 2/(e^2x+1)
  float e = __expf(2.f * x);
  return 1.f - 2.f * __builtin_amdgcn_rcpf(e + 1.f);
}

// issue 16 frags (32 u64 loads, all in flight)
#define FISSUE(base64, va, vb)                                   \
  _Pragma("unroll")                                              \
  for (int j = 0; j < 16; ++j) {                                 \
    const uint64_t* _p = (base64) + j * 8 + cq * 2;              \
    va[j] = al64(_p); vb[j] = al64(_p + 1);                      \
  }
// per-frag: spin-reload if sentinel, then MFMA with weight frag W[j]
#define FCONSUME(base64, va, vb, W)                              \
  _Pragma("unroll")                                              \
  for (int j = 0; j < 16; ++j) {                                 \
    const uint64_t* _p = (base64) + j * 8 + cq * 2;              \
    while (fbad(va[j], vb[j])) { va[j] = al64(_p); vb[j] = al64(_p + 1); } \
    ac[j & 3] = __builtin_amdgcn_mfma_f32_16x16x32_bf16(                   \
        fuse2(va[j], vb[j]), W[j], ac[j & 3], 0, 0, 0);                    \
  }

__device__ __forceinline__ float sel4(f32x4 s, int cq) {
  float r = s[0];
  r = cq == 1 ? s[1] : r;
  r = cq == 2 ? s[2] : r;
  r = cq == 3 ? s[3] : r;
  return r;
}

__device__ void scan_l0(const float* __restrict__ X0, const u16* __restrict__ Whh0,
                        uint32_t* __restrict__ H0b, float* __restrict__ hfin,
                        int slice) {
  const int l = threadIdx.x, n = l & 15, cq = l >> 4;
  const int ng = slice * 16 + n, fb = n & 3;
  bf16x8 bw[16];
  #pragma unroll
  for (int j = 0; j < 16; ++j)
    bw[j] = *(const bf16x8*)&Whh0[(size_t)ng * Hdim + j * 32 + cq * 8];
  uint64_t va[16], vb[16];
  float x0v = X0[((size_t)cq * Tdim) * Hdim + ng];

  #pragma unroll 1
  for (int t = 0; t < Tdim; ++t) {
    float x0n = 0.f;
    if (t + 1 < Tdim) x0n = X0[((size_t)cq * Tdim + t + 1) * Hdim + ng];
    f32x4 ac[4];
    ac[0] = ac[1] = ac[2] = ac[3] = f32x4{0.f, 0.f, 0.f, 0.f};
    if (t > 0) {
      const uint64_t* pb = (const uint64_t*)H0b + (size_t)(t - 1) * 512 + fb * 128;
      FCONSUME(pb, va, vb, bw);
    }
    const f32x4 s4 = (ac[0] + ac[1]) + (ac[2] + ac[3]);
    const float hsel = fast_tanh(sel4(s4, cq) + x0v);   // this lane's batch = cq
    const float hp = __shfl_xor(hsel, 1);
    if (!(n & 1))
      astore(H0b + (size_t)t * 1024 + cq * 256 + (ng >> 1),
             (uint32_t)f2bf(hsel) | ((uint32_t)f2bf(hp) << 16));
    if (t == Tdim - 1) hfin[cq * Hdim + ng] = hsel;
    if (t + 1 < Tdim) {   // pre-issue polls of h0[t] for next iteration
      const uint64_t* pb = (const uint64_t*)H0b + (size_t)t * 512 + fb * 128;
      FISSUE(pb, va, vb);
    }
    x0v = x0n;
  }
}

__device__ void scan_l1(const u16* __restrict__ Wih1, const u16* __restrict__ Whh1,
                        const float* __restrict__ bi1, const float* __restrict__ bi2,
                        uint32_t* __restrict__ H0b, uint32_t* __restrict__ H1b,
                        float* __restrict__ hfin, int slice) {
  const int l = threadIdx.x, n = l & 15, cq = l >> 4;
  const int ng = slice * 16 + n, fb = n & 3;
  bf16x8 bw[16], ww[16];
  #pragma unroll
  for (int j = 0; j < 16; ++j) {
    bw[j] = *(const bf16x8*)&Whh1[(size_t)ng * Hdim + j * 32 + cq * 8];
    ww[j] = *(const bf16x8*)&Wih1[(size_t)ng * Hdim + j * 32 + cq * 8];
  }
  const float bias = bi1[ng] + bi2[ng];
  uint64_t ua[16], ub[16];   // h0[t] frags
  uint64_t wa[16], wb[16];   // h1[t-1] frags
  { const uint64_t* p0 = (const uint64_t*)H0b + fb * 128; FISSUE(p0, ua, ub); }

  #pragma unroll 1
  for (int t = 0; t < Tdim; ++t) {
    if (t > 0) {   // issue self-recurrence polls first (oldest = earliest credit)
      const uint64_t* p1 = (const uint64_t*)H1b + (size_t)(t - 1) * 512 + fb * 128;
      FISSUE(p1, wa, wb);
    }
    f32x4 ac[4];
    ac[0] = f32x4{bias, bias, bias, bias};
    ac[1] = ac[2] = ac[3] = f32x4{0.f, 0.f, 0.f, 0.f};
    // phase P: Wih1 . h0[t]  (operands pre-issued last iter; L0 runs ahead)
    {
      const uint64_t* p0 = (const uint64_t*)H0b + (size_t)t * 512 + fb * 128;
      FCONSUME(p0, ua, ub, ww);
    }
    if (t + 1 < Tdim) {   // re-issue h0 polls for t+1 (arrive during this iter)
      const uint64_t* p0 = (const uint64_t*)H0b + (size_t)(t + 1) * 512 + fb * 128;
      FISSUE(p0, ua, ub);
    }
    // phase R: Whh1 . h1[t-1]  (the true critical chain)
    if (t > 0) {
      const uint64_t* p1 = (const uint64_t*)H1b + (size_t)(t - 1) * 512 + fb * 128;
      FCONSUME(p1, wa, wb, bw);
    }
    const f32x4 s4 = (ac[0] + ac[1]) + (ac[2] + ac[3]);
    const float hsel = fast_tanh(sel4(s4, cq));
    const float hp = __shfl_xor(hsel, 1);
    if (!(n & 1))
      astore(H1b + (size_t)t * 1024 + cq * 256 + (ng >> 1),
             (uint32_t)f2bf(hsel) | ((uint32_t)f2bf(hp) << 16));
    if (t == Tdim - 1) hfin[Bdim * Hdim + cq * Hdim + ng] = hsel;
  }
}

__global__ __launch_bounds__(64) void k_scan(
    const float* __restrict__ X0, const u16* __restrict__ Wihb,
    const u16* __restrict__ Whhb, const float* __restrict__ b_ih,
    const float* __restrict__ b_hh, uint32_t* __restrict__ H0b,
    uint32_t* __restrict__ H1b, float* __restrict__ hfin)
{
  const int blk = blockIdx.x;
  if (blk < 32)
    scan_l0(X0, Whhb, H0b, hfin, blk);
  else
    scan_l1(Wihb + Hdim * Hdim, Whhb + Hdim * Hdim, b_ih + Hdim, b_hh + Hdim,
            H0b, H1b, hfin, blk - 32);
}

// ---------------- launch ----------------
extern "C" void kernel_launch(void* const* d_in, const int* in_sizes, int n_in,
                              void* d_out, int out_size, void* d_ws, size_t ws_size,
                              hipStream_t stream)
{
  const int*   x     = (const int*)d_in[0];
  const float* embed = (const float*)d_in[1];
  const float* W_ih  = (const float*)d_in[2];
  const float* b_ih  = (const float*)d_in[3];
  const float* W_hh  = (const float*)d_in[4];
  const float* b_hh  = (const float*)d_in[5];
  const float* W_out = (const float*)d_in[6];
  const float* b_out = (const float*)d_in[7];
  float* out = (float*)d_out;

  // workspace layout (~74 MB)
  char* ws = (char*)d_ws;
  u16* E       = (u16*)ws;                                  // 8192*512
  u16* Wihb    = E + (size_t)MROWS * Hdim;                  // 2*512*512
  u16* Whhb    = Wihb + 2 * Hdim * Hdim;                    // 2*512*512
  u16* Woutb   = Whhb + 2 * Hdim * Hdim;                    // 32000*512
  float* X0    = (float*)(Woutb + (size_t)Vdim * Hdim);     // 8192*512 f32
  uint32_t* H0b = (uint32_t*)(X0 + (size_t)MROWS * Hdim);   // 2048*1024 dwords
  uint32_t* H1b = H0b + (size_t)Tdim * 1024;

  hipMemsetAsync(H0b, 0xFF, (size_t)Tdim * 1024 * 4, stream);
  hipMemsetAsync(H1b, 0xFF, (size_t)Tdim * 1024 * 4, stream);

  k_gather<<<MROWS * (Hdim / 4) / 256, 256, 0, stream>>>(x, embed, E);
  k_f2b<<<(2 * Hdim * Hdim / 4) / 256, 256, 0, stream>>>(W_ih, Wihb, 2 * Hdim * Hdim / 4);
  k_f2b<<<(2 * Hdim * Hdim / 4) / 256, 256, 0, stream>>>(W_hh, Whhb, 2 * Hdim * Hdim / 4);
  k_f2b<<<((size_t)Vdim * Hdim / 4) / 256, 256, 0, stream>>>(W_out, Woutb, Vdim * Hdim / 4);

  // X0 = E @ Wih0^T + b_ih0 + b_hh0   (rows m = b*T+t)
  k_gemm<<<(MROWS / 128) * (Hdim / 128), 256, 0, stream>>>(
      E, Wihb, X0, b_ih, b_hh, MROWS, Hdim, Hdim, Hdim / 128, 0);

  float* hfin = out + (size_t)MROWS * Vdim;
  k_scan<<<64, 64, 0, stream>>>(X0, Wihb, Whhb, b_ih, b_hh, H0b, H1b, hfin);

  // out = H1 @ W_out^T + b_out   (A in [t][b][n] layout -> aperm=1)
  k_gemm<<<(MROWS / 128) * (Vdim / 128), 256, 0, stream>>>(
      (const u16*)H1b, Woutb, out, b_out, nullptr, MROWS, Vdim, Hdim, Vdim / 128, 1);
}